// Round 14
// baseline (492.501 us; speedup 1.0000x reference)
//
#include <hip/hip_runtime.h>
#include <hip/hip_fp16.h>

#define N_NODES 200000
#define N_EDGES 6400000
#define D_IN    128
#define D_HID   16
#define D_OUT   172

#define NS1     1600      // stage-1 blocks
#define EPB     4000      // edges per stage-1 block: 1600*4000 = 6.4M exactly
#define SBN     782       // superbuckets of 256 nodes: 782*256 = 200192 >= 200001
#define SB_NODES 256

// workspace offsets in 4-byte words (peak 13,202,112 words = 52.8 MB)
#define O_BTOT  0          // u32[782]
#define O_BASE  1024       // u32[783]
#define O_CNT1  2048       // u32[1600*782] raw per-block counts (dead after scatter1)
#define O_SCN   1253248    // u32[1600*782] column-exclusive scans (dead after scatter1)
#define O_COL   2048       // int[6.4M] CSR col ids (k_csr writes; aliases CNT1+SCN)
#define O_ROW   6402048    // int[200001]
#define O_DINV  6602112    // f32[200000]
#define O_PACK  6802112    // u32[6.4M] SB-sorted packed edges (dead after k_csr)
#define O_F16A  6802112    // f16[3.2M] lin1' (aliases PACK)
#define O_F16B  8402112    // f16[3.2M] h'
#define O_AGG2  10002112   // f32[3.2M]

// --- non-temporal helpers: streaming data must not evict the gather table ---
typedef float f32x4 __attribute__((ext_vector_type(4)));
__device__ __forceinline__ int      ntl_i32(const int* p)      { return __builtin_nontemporal_load(p); }
__device__ __forceinline__ unsigned ntl_u32(const unsigned* p) { return __builtin_nontemporal_load(p); }
__device__ __forceinline__ f32x4    ntl_f32x4(const float* p)  { return __builtin_nontemporal_load((const f32x4*)p); }
__device__ __forceinline__ void nts_u32(unsigned* p, unsigned v)    { __builtin_nontemporal_store(v, p); }
__device__ __forceinline__ void nts_f32(float* p, float v)          { __builtin_nontemporal_store(v, p); }
__device__ __forceinline__ void nts_u64(void* p, unsigned long long v) { __builtin_nontemporal_store(v, (unsigned long long*)p); }
__device__ __forceinline__ void nts_f32x4(void* p, f32x4 v)         { __builtin_nontemporal_store(v, (f32x4*)p); }

// ---------------------------------------------------------------------------
__global__ __launch_bounds__(256) void k_hist1(const int* __restrict__ dst,
                                               unsigned* __restrict__ counts) {
    __shared__ unsigned cnt[SBN];
    for (int i = threadIdx.x; i < SBN; i += 256) cnt[i] = 0;
    __syncthreads();
    const int* dp = dst + blockIdx.x * EPB;
    for (int i = threadIdx.x; i < EPB; i += 256)
        atomicAdd(&cnt[ntl_i32(dp + i) >> 8], 1u);
    __syncthreads();
    unsigned* out = counts + (size_t)blockIdx.x * SBN;
    for (int i = threadIdx.x; i < SBN; i += 256) out[i] = cnt[i];
}

// per-column exclusive scan of counts -> scn (counts preserved) + column totals
__global__ __launch_bounds__(256) void k_scan_col(const unsigned* __restrict__ counts,
                                                  unsigned* __restrict__ scn,
                                                  unsigned* __restrict__ btot) {
    __shared__ unsigned arr[NS1];
    int b = blockIdx.x;
    for (int i = threadIdx.x; i < NS1; i += 256)
        arr[i] = counts[(size_t)i * SBN + b];
    __syncthreads();
    if (threadIdx.x < 64) {
        int l = threadIdx.x;
        int lo = l * 25, hi = min(lo + 25, NS1);   // 25*64 = 1600 exactly
        unsigned sum = 0;
        for (int i = lo; i < hi; ++i) sum += arr[i];
        unsigned incl = sum;
#pragma unroll
        for (int o = 1; o < 64; o <<= 1) {
            unsigned tmp = __shfl_up(incl, o);
            if (l >= o) incl += tmp;
        }
        if (l == 63) btot[b] = incl;
        unsigned run = incl - sum;
        for (int i = lo; i < hi; ++i) { unsigned v = arr[i]; arr[i] = run; run += v; }
    }
    __syncthreads();
    for (int i = threadIdx.x; i < NS1; i += 256)
        scn[(size_t)i * SBN + b] = arr[i];
}

__global__ __launch_bounds__(64) void k_scan_base(const unsigned* __restrict__ btot,
                                                  unsigned* __restrict__ base) {
    int l = threadIdx.x;
    int lo = l * 13, hi = min(lo + 13, SBN);       // 13*64 = 832 >= 782
    unsigned sum = 0;
    for (int i = lo; i < hi; ++i) sum += btot[i];
    unsigned incl = sum;
#pragma unroll
    for (int o = 1; o < 64; o <<= 1) {
        unsigned tmp = __shfl_up(incl, o);
        if (l >= o) incl += tmp;
    }
    unsigned run = incl - sum;
    for (int i = lo; i < hi; ++i) { unsigned v = btot[i]; base[i] = run; run += v; }
    if (l == 63) base[SBN] = incl;                  // = N_EDGES
}

// block-local LDS counting sort (counts from k_hist1, no re-histogram),
// then contiguous coalesced write-out. EPB=4000 -> 33.4 KB LDS, 4 blocks/CU.
__global__ __launch_bounds__(256) void k_scatter1(const int* __restrict__ src,
                                                  const int* __restrict__ dst,
                                                  const unsigned* __restrict__ counts,
                                                  const unsigned* __restrict__ scn,
                                                  const unsigned* __restrict__ base,
                                                  unsigned* __restrict__ packed) {
    __shared__ unsigned       sdat[EPB];   // 16.0 KB sorted payloads
    __shared__ unsigned short sbkt[EPB];   //  8.0 KB bucket id per slot
    __shared__ unsigned cnt[SBN];
    __shared__ unsigned off[SBN];
    __shared__ unsigned gbs[SBN];
    __shared__ unsigned wsum[4];
    int t = threadIdx.x;
    const unsigned* crow = counts + (size_t)blockIdx.x * SBN;  // raw counts
    const unsigned* srow = scn    + (size_t)blockIdx.x * SBN;  // excl. scans
    for (int i = t; i < SBN; i += 256) {
        cnt[i] = crow[i];
        gbs[i] = base[i] + srow[i];
    }
    __syncthreads();
    // exclusive scan cnt -> off (thread owns 4 bins)
    int lane = t & 63, wid = t >> 6;
    int b0 = t * 4;
    unsigned c0v = (b0 + 0 < SBN) ? cnt[b0 + 0] : 0;
    unsigned c1v = (b0 + 1 < SBN) ? cnt[b0 + 1] : 0;
    unsigned c2v = (b0 + 2 < SBN) ? cnt[b0 + 2] : 0;
    unsigned c3v = (b0 + 3 < SBN) ? cnt[b0 + 3] : 0;
    unsigned mysum = c0v + c1v + c2v + c3v;
    unsigned incl = mysum;
#pragma unroll
    for (int o = 1; o < 64; o <<= 1) {
        unsigned tmp = __shfl_up(incl, o);
        if (lane >= o) incl += tmp;
    }
    if (lane == 63) wsum[wid] = incl;
    __syncthreads();
    unsigned wbase = 0;
    for (int w = 0; w < wid; ++w) wbase += wsum[w];
    unsigned run = wbase + incl - mysum;
    if (b0 + 0 < SBN) { off[b0 + 0] = run; run += c0v; }
    if (b0 + 1 < SBN) { off[b0 + 1] = run; run += c1v; }
    if (b0 + 2 < SBN) { off[b0 + 2] = run; run += c2v; }
    if (b0 + 3 < SBN) { off[b0 + 3] = run; run += c3v; }
    __syncthreads();
    const int* sp = src + blockIdx.x * EPB;
    const int* dp = dst + blockIdx.x * EPB;
    for (int i = t; i < EPB; i += 256) {
        int s = ntl_i32(sp + i), d = ntl_i32(dp + i);
        unsigned b = (unsigned)d >> 8;
        unsigned slot = atomicAdd(&off[b], 1u);
        sdat[slot] = ((unsigned)(d & (SB_NODES - 1)) << 18) | (unsigned)s;
        sbkt[slot] = (unsigned short)b;
    }
    __syncthreads();
    for (int i = t; i < EPB; i += 256) {
        unsigned b = sbkt[i];
        unsigned start = off[b] - cnt[b];          // off now = end cursor
        nts_u32(&packed[gbs[b] + (i - start)], sdat[i]);
    }
}

// one 256-thread block per 256-node SB -> rowptr, col, dinv
__global__ __launch_bounds__(256) void k_csr(const unsigned* __restrict__ packed,
                                             const unsigned* __restrict__ base,
                                             int* __restrict__ rowptr,
                                             float* __restrict__ dinv,
                                             int* __restrict__ col) {
    __shared__ unsigned cnt[SB_NODES];
    __shared__ unsigned off[SB_NODES];
    __shared__ unsigned wsum[4];
    int t = threadIdx.x, sb = blockIdx.x;
    unsigned beg = base[sb], end = base[sb + 1];
    cnt[t] = 0;
    __syncthreads();
    for (unsigned i = beg + t; i < end; i += 256)
        atomicAdd(&cnt[ntl_u32(packed + i) >> 18], 1u);
    __syncthreads();
    unsigned e = cnt[t];
    int lane = t & 63, wid = t >> 6;
    unsigned incl = e;
#pragma unroll
    for (int o = 1; o < 64; o <<= 1) {
        unsigned tmp = __shfl_up(incl, o);
        if (lane >= o) incl += tmp;
    }
    if (lane == 63) wsum[wid] = incl;
    __syncthreads();
    unsigned wbase = 0;
    for (int w = 0; w < wid; ++w) wbase += wsum[w];
    unsigned ex = wbase + incl - e;
    off[t] = ex;
    int n0 = sb * SB_NODES + t;
    if (n0 <= N_NODES) rowptr[n0] = (int)(beg + ex);
    if (n0 <  N_NODES) dinv[n0]   = rsqrtf((float)(e + 1));
    __syncthreads();
    for (unsigned i = beg + t; i < end; i += 256) {
        unsigned p = ntl_u32(packed + i);
        unsigned slot = atomicAdd(&off[p >> 18], 1u);
        col[beg + slot] = (int)(p & 0x3FFFFu);
    }
}

// ---------------------------------------------------------------------------
// lin' = (x @ W1) * dinv[n], stored fp16. x is 102 MB read-once -> NT loads.
__global__ __launch_bounds__(256) void k_lin1(const float* __restrict__ x,
                                              const float* __restrict__ W1,
                                              const float* __restrict__ dinv,
                                              __half* __restrict__ lin) {
    __shared__ float sW[D_IN * D_HID];
    for (int t = threadIdx.x; t < D_IN * D_HID; t += 256) sW[t] = W1[t];
    __syncthreads();

    int g  = threadIdx.x & 3;
    int nl = threadIdx.x >> 2;
    int n  = blockIdx.x * 64 + nl;   // grid exact: 3125*64

    float acc[16];
#pragma unroll
    for (int j = 0; j < 16; ++j) acc[j] = 0.f;

    const float* xr = x + (size_t)n * D_IN + g * 32;
#pragma unroll
    for (int i = 0; i < 8; ++i) {
        f32x4 xv = ntl_f32x4(xr + i * 4);
        int k = g * 32 + i * 4;
#pragma unroll
        for (int j = 0; j < 16; ++j) {
            acc[j] += xv.x * sW[(k + 0) * 16 + j] + xv.y * sW[(k + 1) * 16 + j]
                    + xv.z * sW[(k + 2) * 16 + j] + xv.w * sW[(k + 3) * 16 + j];
        }
    }
#pragma unroll
    for (int j = 0; j < 16; ++j) {
        acc[j] += __shfl_xor(acc[j], 1);
        acc[j] += __shfl_xor(acc[j], 2);
    }
    float di = dinv[n];
    ushort4 pk;
    pk.x = __half_as_ushort(__float2half(acc[g * 4 + 0] * di));
    pk.y = __half_as_ushort(__float2half(acc[g * 4 + 1] * di));
    pk.z = __half_as_ushort(__float2half(acc[g * 4 + 2] * di));
    pk.w = __half_as_ushort(__float2half(acc[g * 4 + 3] * di));
    *(ushort4*)(lin + (size_t)n * 16 + g * 4) = pk;   // table: keep cached
}

// ---------------------------------------------------------------------------
// pull-gather v4: 4 lanes/node (lane owns 4 features = one 8B uint2),
// 16 nodes/wave, 8 edges in flight/lane. col = streaming -> NT loads;
// output = streaming -> NT stores; table (fin) stays cached.
// MODE 1: v = relu(acc*dd + b1)*dd -> fp16 out.  MODE 0: v = acc*dd -> f32 out.
#define H2F2(u) __half22float2(*(const __half2*)&(u))
template <int MODE>
__global__ __launch_bounds__(256) void k_gather(const int* __restrict__ rowptr,
                                                const int* __restrict__ col,
                                                const float* __restrict__ dinv,
                                                const uint2* __restrict__ fin,
                                                const float* __restrict__ bias,
                                                void* __restrict__ outv) {
    int t = threadIdx.x;
    int n = blockIdx.x * 64 + (t >> 2);   // 64 nodes/block, grid exact: 3125*64
    int lane = t & 3;                     // owns features 4*lane .. 4*lane+3
    int beg = rowptr[n], end = rowptr[n + 1];
    uint2 su = fin[n * 4 + lane];          // self loop (pre-scaled)
    float2 sl0 = H2F2(su.x), sl1 = H2F2(su.y);
    float ax0 = sl0.x, ay0 = sl0.y, az0 = sl1.x, aw0 = sl1.y;
    float ax1 = 0, ay1 = 0, az1 = 0, aw1 = 0;
    float ax2 = 0, ay2 = 0, az2 = 0, aw2 = 0;
    float ax3 = 0, ay3 = 0, az3 = 0, aw3 = 0;
    float ax4 = 0, ay4 = 0, az4 = 0, aw4 = 0;
    float ax5 = 0, ay5 = 0, az5 = 0, aw5 = 0;
    float ax6 = 0, ay6 = 0, az6 = 0, aw6 = 0;
    float ax7 = 0, ay7 = 0, az7 = 0, aw7 = 0;
    int i = beg;
    for (; i + 8 <= end; i += 8) {
        int s0 = ntl_i32(col + i + 0), s1 = ntl_i32(col + i + 1);
        int s2 = ntl_i32(col + i + 2), s3 = ntl_i32(col + i + 3);
        int s4 = ntl_i32(col + i + 4), s5 = ntl_i32(col + i + 5);
        int s6 = ntl_i32(col + i + 6), s7 = ntl_i32(col + i + 7);
        uint2 h0 = fin[s0 * 4 + lane], h1 = fin[s1 * 4 + lane];
        uint2 h2 = fin[s2 * 4 + lane], h3 = fin[s3 * 4 + lane];
        uint2 h4 = fin[s4 * 4 + lane], h5 = fin[s5 * 4 + lane];
        uint2 h6 = fin[s6 * 4 + lane], h7 = fin[s7 * 4 + lane];
        float2 l0 = H2F2(h0.x), m0 = H2F2(h0.y);
        float2 l1 = H2F2(h1.x), m1 = H2F2(h1.y);
        float2 l2 = H2F2(h2.x), m2 = H2F2(h2.y);
        float2 l3 = H2F2(h3.x), m3 = H2F2(h3.y);
        float2 l4 = H2F2(h4.x), m4 = H2F2(h4.y);
        float2 l5 = H2F2(h5.x), m5 = H2F2(h5.y);
        float2 l6 = H2F2(h6.x), m6 = H2F2(h6.y);
        float2 l7 = H2F2(h7.x), m7 = H2F2(h7.y);
        ax0 += l0.x; ay0 += l0.y; az0 += m0.x; aw0 += m0.y;
        ax1 += l1.x; ay1 += l1.y; az1 += m1.x; aw1 += m1.y;
        ax2 += l2.x; ay2 += l2.y; az2 += m2.x; aw2 += m2.y;
        ax3 += l3.x; ay3 += l3.y; az3 += m3.x; aw3 += m3.y;
        ax4 += l4.x; ay4 += l4.y; az4 += m4.x; aw4 += m4.y;
        ax5 += l5.x; ay5 += l5.y; az5 += m5.x; aw5 += m5.y;
        ax6 += l6.x; ay6 += l6.y; az6 += m6.x; aw6 += m6.y;
        ax7 += l7.x; ay7 += l7.y; az7 += m7.x; aw7 += m7.y;
    }
    for (; i < end; ++i) {
        uint2 h = fin[ntl_i32(col + i) * 4 + lane];
        float2 l = H2F2(h.x), m = H2F2(h.y);
        ax0 += l.x; ay0 += l.y; az0 += m.x; aw0 += m.y;
    }
    float vx = ((ax0 + ax1) + (ax2 + ax3)) + ((ax4 + ax5) + (ax6 + ax7));
    float vy = ((ay0 + ay1) + (ay2 + ay3)) + ((ay4 + ay5) + (ay6 + ay7));
    float vz = ((az0 + az1) + (az2 + az3)) + ((az4 + az5) + (az6 + az7));
    float vw = ((aw0 + aw1) + (aw2 + aw3)) + ((aw4 + aw5) + (aw6 + aw7));
    float dd = dinv[n];
    vx *= dd; vy *= dd; vz *= dd; vw *= dd;
    if (MODE) {
        float4 b4 = ((const float4*)bias)[lane];
        vx = fmaxf(vx + b4.x, 0.f) * dd;
        vy = fmaxf(vy + b4.y, 0.f) * dd;
        vz = fmaxf(vz + b4.z, 0.f) * dd;
        vw = fmaxf(vw + b4.w, 0.f) * dd;
        __half2 o0 = __floats2half2_rn(vx, vy), o1 = __floats2half2_rn(vz, vw);
        unsigned long long ov = ((unsigned long long)*(const unsigned*)&o1 << 32)
                              |  (unsigned long long)*(const unsigned*)&o0;
        nts_u64((uint2*)outv + n * 4 + lane, ov);
    } else {
        f32x4 o = {vx, vy, vz, vw};
        nts_f32x4((float*)outv + (size_t)n * 16 + lane * 4, o);
    }
}

// ---------------------------------------------------------------------------
// k_out v4: wave = 64 nodes (thread = node); wave w owns classes c = w + 4i
// (wave-uniform -> W2/b2 scalar loads). Pass A: logits -> fp16 LDS + fmax only.
// Pass B: exp-sum with final max. agg2 NT-load; out NT-store (write-once).
#define SLP 174   // fp16 pad stride
__global__ __launch_bounds__(256) void k_out(const float* __restrict__ agg2,
                                             const float* __restrict__ W2,
                                             const float* __restrict__ b2,
                                             float* __restrict__ out) {
    __shared__ __half sl[64 * SLP];  // 22.3 KB logits [node][class] fp16
    __shared__ float pm[4][64];      // per-wave partial max
    __shared__ float ps[4][64];      // per-wave partial sumexp
    __shared__ float sls[64];        // per-node logsumexp
    int t   = threadIdx.x;
    int wid = __builtin_amdgcn_readfirstlane(t >> 6);  // wave id 0..3 (SGPR)
    int nl  = t & 63;
    int n   = blockIdx.x * 64 + nl;                    // grid exact: 3125*64

    const float* ap = agg2 + (size_t)n * 16;
    f32x4 a0 = ntl_f32x4(ap), a1 = ntl_f32x4(ap + 4);
    f32x4 a2 = ntl_f32x4(ap + 8), a3 = ntl_f32x4(ap + 12);
    float a[16] = {a0.x, a0.y, a0.z, a0.w, a1.x, a1.y, a1.z, a1.w,
                   a2.x, a2.y, a2.z, a2.w, a3.x, a3.y, a3.z, a3.w};

    float m = -INFINITY;
    __half* srow = sl + nl * SLP;
    for (int i = 0; i < 43; ++i) {             // c = wid + 4i <= 171 always
        int c = wid + 4 * i;                   // wave-uniform -> s_load W2
        float l = b2[c];
#pragma unroll
        for (int k = 0; k < 16; ++k) l += a[k] * W2[k * D_OUT + c];
        srow[c] = __float2half(l);
        m = fmaxf(m, l);
    }
    pm[wid][nl] = m;
    __syncthreads();
    float M = fmaxf(fmaxf(pm[0][nl], pm[1][nl]), fmaxf(pm[2][nl], pm[3][nl]));
    float s = 0.f;
    for (int i = 0; i < 43; ++i)
        s += __expf(__half2float(srow[wid + 4 * i]) - M);
    ps[wid][nl] = s;
    __syncthreads();
    if (wid == 0)
        sls[nl] = M + __logf(ps[0][nl] + ps[1][nl] + ps[2][nl] + ps[3][nl]);
    __syncthreads();
    // coalesced copy-out (log_softmax of the fp16-rounded logits: consistent)
    float* ob = out + (size_t)blockIdx.x * 64 * D_OUT;
    for (int idx = t; idx < 64 * D_OUT; idx += 256) {
        int node = idx / D_OUT, c = idx - node * D_OUT;
        nts_f32(ob + idx, __half2float(sl[node * SLP + c]) - sls[node]);
    }
}

// ---------------------------------------------------------------------------
extern "C" void kernel_launch(void* const* d_in, const int* in_sizes, int n_in,
                              void* d_out, int out_size, void* d_ws, size_t ws_size,
                              hipStream_t stream) {
    const float* x     = (const float*)d_in[0];
    const int*   edges = (const int*)d_in[1];
    const float* W1    = (const float*)d_in[2];
    const float* b1    = (const float*)d_in[3];
    const float* W2    = (const float*)d_in[4];
    const float* b2    = (const float*)d_in[5];
    float*       out   = (float*)d_out;

    const int* src = edges;
    const int* dst = edges + N_EDGES;

    unsigned* ws     = (unsigned*)d_ws;
    unsigned* btot   = ws + O_BTOT;
    unsigned* base   = ws + O_BASE;
    unsigned* counts = ws + O_CNT1;
    unsigned* scn    = ws + O_SCN;
    int*      col    = (int*)(ws + O_COL);      // aliases counts+scn (dead)
    int*      rowptr = (int*)(ws + O_ROW);
    float*    dinv   = (float*)(ws + O_DINV);
    unsigned* packed = ws + O_PACK;             // dead after k_csr
    __half*   f16a   = (__half*)(ws + O_F16A);  // aliases packed
    __half*   f16b   = (__half*)(ws + O_F16B);
    float*    agg2   = (float*)(ws + O_AGG2);

    // --- CSR build: zero global atomics ---
    k_hist1    <<<NS1, 256, 0, stream>>>(dst, counts);
    k_scan_col <<<SBN, 256, 0, stream>>>(counts, scn, btot);
    k_scan_base<<<1,    64, 0, stream>>>(btot, base);
    k_scatter1 <<<NS1, 256, 0, stream>>>(src, dst, counts, scn, base, packed);
    k_csr      <<<SBN, 256, 0, stream>>>(packed, base, rowptr, dinv, col);

    // --- layer 1: project 128->16 (pre-scaled, fp16), gather (relu fused) ---
    k_lin1     <<<N_NODES / 64, 256, 0, stream>>>(x, W1, dinv, f16a);
    k_gather<1><<<N_NODES / 64, 256, 0, stream>>>(rowptr, col, dinv,
                                                  (const uint2*)f16a, b1, f16b);

    // --- layer 2 (reassociated): gather h', then 16->172 + log_softmax ---
    k_gather<0><<<N_NODES / 64, 256, 0, stream>>>(rowptr, col, dinv,
                                                  (const uint2*)f16b, b1, agg2);
    k_out      <<<N_NODES / 64, 256, 0, stream>>>(agg2, W2, b2, out);
}

// Round 15
// 394.514 us; speedup vs baseline: 1.2484x; 1.2484x over previous
//
#include <hip/hip_runtime.h>
#include <hip/hip_fp16.h>

#define N_NODES 200000
#define N_EDGES 6400000
#define D_IN    128
#define D_HID   16
#define D_OUT   172

#define NS1     1600      // stage-1 blocks
#define EPB     4000      // edges per stage-1 block: 1600*4000 = 6.4M exactly
#define SBN     782       // superbuckets of 256 nodes: 782*256 = 200192 >= 200001
#define SB_NODES 256

// workspace offsets in 4-byte words (peak 13,202,112 words = 52.8 MB)
#define O_BTOT  0          // u32[782]
#define O_BASE  1024       // u32[783]
#define O_CNT1  2048       // u32[1600*782] raw per-block counts (dead after scatter1)
#define O_SCN   1253248    // u32[1600*782] column-exclusive scans (dead after scatter1)
#define O_COL   2048       // int[6.4M] CSR col ids (k_csr writes; aliases CNT1+SCN)
#define O_ROW   6402048    // int[200001]
#define O_DINV  6602112    // f32[200000]
#define O_PACK  6802112    // u32[6.4M] SB-sorted packed edges (dead after k_csr)
#define O_F16A  6802112    // f16[3.2M] lin1' (aliases PACK)
#define O_F16B  8402112    // f16[3.2M] h'
#define O_AGG2  10002112   // f32[3.2M]

// NT loads ONLY for x in k_lin1: read exactly once, never re-read by any
// kernel. (R14 lesson: packed/col/agg2 are inter-kernel cache-resident
// temporaries -- NT on them forces HBM round-trips and cost +100 us.)
typedef float f32x4 __attribute__((ext_vector_type(4)));
__device__ __forceinline__ f32x4 ntl_f32x4(const float* p) {
    return __builtin_nontemporal_load((const f32x4*)p);
}

// ---------------------------------------------------------------------------
__global__ __launch_bounds__(256) void k_hist1(const int* __restrict__ dst,
                                               unsigned* __restrict__ counts) {
    __shared__ unsigned cnt[SBN];
    for (int i = threadIdx.x; i < SBN; i += 256) cnt[i] = 0;
    __syncthreads();
    const int* dp = dst + blockIdx.x * EPB;
    for (int i = threadIdx.x; i < EPB; i += 256)
        atomicAdd(&cnt[dp[i] >> 8], 1u);
    __syncthreads();
    unsigned* out = counts + (size_t)blockIdx.x * SBN;
    for (int i = threadIdx.x; i < SBN; i += 256) out[i] = cnt[i];
}

// per-column exclusive scan of counts -> scn (counts preserved) + column totals
__global__ __launch_bounds__(256) void k_scan_col(const unsigned* __restrict__ counts,
                                                  unsigned* __restrict__ scn,
                                                  unsigned* __restrict__ btot) {
    __shared__ unsigned arr[NS1];
    int b = blockIdx.x;
    for (int i = threadIdx.x; i < NS1; i += 256)
        arr[i] = counts[(size_t)i * SBN + b];
    __syncthreads();
    if (threadIdx.x < 64) {
        int l = threadIdx.x;
        int lo = l * 25, hi = min(lo + 25, NS1);   // 25*64 = 1600 exactly
        unsigned sum = 0;
        for (int i = lo; i < hi; ++i) sum += arr[i];
        unsigned incl = sum;
#pragma unroll
        for (int o = 1; o < 64; o <<= 1) {
            unsigned tmp = __shfl_up(incl, o);
            if (l >= o) incl += tmp;
        }
        if (l == 63) btot[b] = incl;
        unsigned run = incl - sum;
        for (int i = lo; i < hi; ++i) { unsigned v = arr[i]; arr[i] = run; run += v; }
    }
    __syncthreads();
    for (int i = threadIdx.x; i < NS1; i += 256)
        scn[(size_t)i * SBN + b] = arr[i];
}

__global__ __launch_bounds__(64) void k_scan_base(const unsigned* __restrict__ btot,
                                                  unsigned* __restrict__ base) {
    int l = threadIdx.x;
    int lo = l * 13, hi = min(lo + 13, SBN);       // 13*64 = 832 >= 782
    unsigned sum = 0;
    for (int i = lo; i < hi; ++i) sum += btot[i];
    unsigned incl = sum;
#pragma unroll
    for (int o = 1; o < 64; o <<= 1) {
        unsigned tmp = __shfl_up(incl, o);
        if (l >= o) incl += tmp;
    }
    unsigned run = incl - sum;
    for (int i = lo; i < hi; ++i) { unsigned v = btot[i]; base[i] = run; run += v; }
    if (l == 63) base[SBN] = incl;                  // = N_EDGES
}

// block-local LDS counting sort (counts from k_hist1, no re-histogram),
// then contiguous coalesced write-out. EPB=4000 -> 33.4 KB LDS, 4 blocks/CU.
__global__ __launch_bounds__(256) void k_scatter1(const int* __restrict__ src,
                                                  const int* __restrict__ dst,
                                                  const unsigned* __restrict__ counts,
                                                  const unsigned* __restrict__ scn,
                                                  const unsigned* __restrict__ base,
                                                  unsigned* __restrict__ packed) {
    __shared__ unsigned       sdat[EPB];   // 16.0 KB sorted payloads
    __shared__ unsigned short sbkt[EPB];   //  8.0 KB bucket id per slot
    __shared__ unsigned cnt[SBN];
    __shared__ unsigned off[SBN];
    __shared__ unsigned gbs[SBN];
    __shared__ unsigned wsum[4];
    int t = threadIdx.x;
    const unsigned* crow = counts + (size_t)blockIdx.x * SBN;  // raw counts
    const unsigned* srow = scn    + (size_t)blockIdx.x * SBN;  // excl. scans
    for (int i = t; i < SBN; i += 256) {
        cnt[i] = crow[i];
        gbs[i] = base[i] + srow[i];
    }
    __syncthreads();
    // exclusive scan cnt -> off (thread owns 4 bins)
    int lane = t & 63, wid = t >> 6;
    int b0 = t * 4;
    unsigned c0v = (b0 + 0 < SBN) ? cnt[b0 + 0] : 0;
    unsigned c1v = (b0 + 1 < SBN) ? cnt[b0 + 1] : 0;
    unsigned c2v = (b0 + 2 < SBN) ? cnt[b0 + 2] : 0;
    unsigned c3v = (b0 + 3 < SBN) ? cnt[b0 + 3] : 0;
    unsigned mysum = c0v + c1v + c2v + c3v;
    unsigned incl = mysum;
#pragma unroll
    for (int o = 1; o < 64; o <<= 1) {
        unsigned tmp = __shfl_up(incl, o);
        if (lane >= o) incl += tmp;
    }
    if (lane == 63) wsum[wid] = incl;
    __syncthreads();
    unsigned wbase = 0;
    for (int w = 0; w < wid; ++w) wbase += wsum[w];
    unsigned run = wbase + incl - mysum;
    if (b0 + 0 < SBN) { off[b0 + 0] = run; run += c0v; }
    if (b0 + 1 < SBN) { off[b0 + 1] = run; run += c1v; }
    if (b0 + 2 < SBN) { off[b0 + 2] = run; run += c2v; }
    if (b0 + 3 < SBN) { off[b0 + 3] = run; run += c3v; }
    __syncthreads();
    const int* sp = src + blockIdx.x * EPB;
    const int* dp = dst + blockIdx.x * EPB;
    for (int i = t; i < EPB; i += 256) {
        int s = sp[i], d = dp[i];
        unsigned b = (unsigned)d >> 8;
        unsigned slot = atomicAdd(&off[b], 1u);
        sdat[slot] = ((unsigned)(d & (SB_NODES - 1)) << 18) | (unsigned)s;
        sbkt[slot] = (unsigned short)b;
    }
    __syncthreads();
    for (int i = t; i < EPB; i += 256) {
        unsigned b = sbkt[i];
        unsigned start = off[b] - cnt[b];          // off now = end cursor
        packed[gbs[b] + (i - start)] = sdat[i];
    }
}

// one 256-thread block per 256-node SB -> rowptr, col, dinv
__global__ __launch_bounds__(256) void k_csr(const unsigned* __restrict__ packed,
                                             const unsigned* __restrict__ base,
                                             int* __restrict__ rowptr,
                                             float* __restrict__ dinv,
                                             int* __restrict__ col) {
    __shared__ unsigned cnt[SB_NODES];
    __shared__ unsigned off[SB_NODES];
    __shared__ unsigned wsum[4];
    int t = threadIdx.x, sb = blockIdx.x;
    unsigned beg = base[sb], end = base[sb + 1];
    cnt[t] = 0;
    __syncthreads();
    for (unsigned i = beg + t; i < end; i += 256)
        atomicAdd(&cnt[packed[i] >> 18], 1u);
    __syncthreads();
    unsigned e = cnt[t];
    int lane = t & 63, wid = t >> 6;
    unsigned incl = e;
#pragma unroll
    for (int o = 1; o < 64; o <<= 1) {
        unsigned tmp = __shfl_up(incl, o);
        if (lane >= o) incl += tmp;
    }
    if (lane == 63) wsum[wid] = incl;
    __syncthreads();
    unsigned wbase = 0;
    for (int w = 0; w < wid; ++w) wbase += wsum[w];
    unsigned ex = wbase + incl - e;
    off[t] = ex;
    int n0 = sb * SB_NODES + t;
    if (n0 <= N_NODES) rowptr[n0] = (int)(beg + ex);
    if (n0 <  N_NODES) dinv[n0]   = rsqrtf((float)(e + 1));
    __syncthreads();
    for (unsigned i = beg + t; i < end; i += 256) {
        unsigned p = packed[i];
        unsigned slot = atomicAdd(&off[p >> 18], 1u);
        col[beg + slot] = (int)(p & 0x3FFFFu);
    }
}

// ---------------------------------------------------------------------------
// lin' = (x @ W1) * dinv[n], stored fp16. x = 102 MB read-once -> NT loads
// (keeps x out of L2 so the f16a table being written stays resident).
__global__ __launch_bounds__(256) void k_lin1(const float* __restrict__ x,
                                              const float* __restrict__ W1,
                                              const float* __restrict__ dinv,
                                              __half* __restrict__ lin) {
    __shared__ float sW[D_IN * D_HID];
    for (int t = threadIdx.x; t < D_IN * D_HID; t += 256) sW[t] = W1[t];
    __syncthreads();

    int g  = threadIdx.x & 3;
    int nl = threadIdx.x >> 2;
    int n  = blockIdx.x * 64 + nl;   // grid exact: 3125*64

    float acc[16];
#pragma unroll
    for (int j = 0; j < 16; ++j) acc[j] = 0.f;

    const float* xr = x + (size_t)n * D_IN + g * 32;
#pragma unroll
    for (int i = 0; i < 8; ++i) {
        f32x4 xv = ntl_f32x4(xr + i * 4);
        int k = g * 32 + i * 4;
#pragma unroll
        for (int j = 0; j < 16; ++j) {
            acc[j] += xv.x * sW[(k + 0) * 16 + j] + xv.y * sW[(k + 1) * 16 + j]
                    + xv.z * sW[(k + 2) * 16 + j] + xv.w * sW[(k + 3) * 16 + j];
        }
    }
#pragma unroll
    for (int j = 0; j < 16; ++j) {
        acc[j] += __shfl_xor(acc[j], 1);
        acc[j] += __shfl_xor(acc[j], 2);
    }
    float di = dinv[n];
    ushort4 pk;
    pk.x = __half_as_ushort(__float2half(acc[g * 4 + 0] * di));
    pk.y = __half_as_ushort(__float2half(acc[g * 4 + 1] * di));
    pk.z = __half_as_ushort(__float2half(acc[g * 4 + 2] * di));
    pk.w = __half_as_ushort(__float2half(acc[g * 4 + 3] * di));
    *(ushort4*)(lin + (size_t)n * 16 + g * 4) = pk;   // table: keep cached
}

// ---------------------------------------------------------------------------
// pull-gather v4: 4 lanes/node (lane owns 4 features = one 8B uint2),
// 16 nodes/wave, 8 edges in flight/lane -> 128 outstanding requests/wave.
// MODE 1: v = relu(acc*dd + b1)*dd -> fp16 out.  MODE 0: v = acc*dd -> f32 out.
#define H2F2(u) __half22float2(*(const __half2*)&(u))
template <int MODE>
__global__ __launch_bounds__(256) void k_gather(const int* __restrict__ rowptr,
                                                const int* __restrict__ col,
                                                const float* __restrict__ dinv,
                                                const uint2* __restrict__ fin,
                                                const float* __restrict__ bias,
                                                void* __restrict__ outv) {
    int t = threadIdx.x;
    int n = blockIdx.x * 64 + (t >> 2);   // 64 nodes/block, grid exact: 3125*64
    int lane = t & 3;                     // owns features 4*lane .. 4*lane+3
    int beg = rowptr[n], end = rowptr[n + 1];
    uint2 su = fin[n * 4 + lane];          // self loop (pre-scaled)
    float2 sl0 = H2F2(su.x), sl1 = H2F2(su.y);
    float ax0 = sl0.x, ay0 = sl0.y, az0 = sl1.x, aw0 = sl1.y;
    float ax1 = 0, ay1 = 0, az1 = 0, aw1 = 0;
    float ax2 = 0, ay2 = 0, az2 = 0, aw2 = 0;
    float ax3 = 0, ay3 = 0, az3 = 0, aw3 = 0;
    float ax4 = 0, ay4 = 0, az4 = 0, aw4 = 0;
    float ax5 = 0, ay5 = 0, az5 = 0, aw5 = 0;
    float ax6 = 0, ay6 = 0, az6 = 0, aw6 = 0;
    float ax7 = 0, ay7 = 0, az7 = 0, aw7 = 0;
    int i = beg;
    for (; i + 8 <= end; i += 8) {
        int s0 = col[i + 0], s1 = col[i + 1], s2 = col[i + 2], s3 = col[i + 3];
        int s4 = col[i + 4], s5 = col[i + 5], s6 = col[i + 6], s7 = col[i + 7];
        uint2 h0 = fin[s0 * 4 + lane], h1 = fin[s1 * 4 + lane];
        uint2 h2 = fin[s2 * 4 + lane], h3 = fin[s3 * 4 + lane];
        uint2 h4 = fin[s4 * 4 + lane], h5 = fin[s5 * 4 + lane];
        uint2 h6 = fin[s6 * 4 + lane], h7 = fin[s7 * 4 + lane];
        float2 l0 = H2F2(h0.x), m0 = H2F2(h0.y);
        float2 l1 = H2F2(h1.x), m1 = H2F2(h1.y);
        float2 l2 = H2F2(h2.x), m2 = H2F2(h2.y);
        float2 l3 = H2F2(h3.x), m3 = H2F2(h3.y);
        float2 l4 = H2F2(h4.x), m4 = H2F2(h4.y);
        float2 l5 = H2F2(h5.x), m5 = H2F2(h5.y);
        float2 l6 = H2F2(h6.x), m6 = H2F2(h6.y);
        float2 l7 = H2F2(h7.x), m7 = H2F2(h7.y);
        ax0 += l0.x; ay0 += l0.y; az0 += m0.x; aw0 += m0.y;
        ax1 += l1.x; ay1 += l1.y; az1 += m1.x; aw1 += m1.y;
        ax2 += l2.x; ay2 += l2.y; az2 += m2.x; aw2 += m2.y;
        ax3 += l3.x; ay3 += l3.y; az3 += m3.x; aw3 += m3.y;
        ax4 += l4.x; ay4 += l4.y; az4 += m4.x; aw4 += m4.y;
        ax5 += l5.x; ay5 += l5.y; az5 += m5.x; aw5 += m5.y;
        ax6 += l6.x; ay6 += l6.y; az6 += m6.x; aw6 += m6.y;
        ax7 += l7.x; ay7 += l7.y; az7 += m7.x; aw7 += m7.y;
    }
    for (; i < end; ++i) {
        uint2 h = fin[col[i] * 4 + lane];
        float2 l = H2F2(h.x), m = H2F2(h.y);
        ax0 += l.x; ay0 += l.y; az0 += m.x; aw0 += m.y;
    }
    float vx = ((ax0 + ax1) + (ax2 + ax3)) + ((ax4 + ax5) + (ax6 + ax7));
    float vy = ((ay0 + ay1) + (ay2 + ay3)) + ((ay4 + ay5) + (ay6 + ay7));
    float vz = ((az0 + az1) + (az2 + az3)) + ((az4 + az5) + (az6 + az7));
    float vw = ((aw0 + aw1) + (aw2 + aw3)) + ((aw4 + aw5) + (aw6 + aw7));
    float dd = dinv[n];
    vx *= dd; vy *= dd; vz *= dd; vw *= dd;
    if (MODE) {
        float4 b4 = ((const float4*)bias)[lane];
        vx = fmaxf(vx + b4.x, 0.f) * dd;
        vy = fmaxf(vy + b4.y, 0.f) * dd;
        vz = fmaxf(vz + b4.z, 0.f) * dd;
        vw = fmaxf(vw + b4.w, 0.f) * dd;
        __half2 o0 = __floats2half2_rn(vx, vy), o1 = __floats2half2_rn(vz, vw);
        uint2 o; o.x = *(const unsigned*)&o0; o.y = *(const unsigned*)&o1;
        ((uint2*)outv)[n * 4 + lane] = o;
    } else {
        ((float4*)outv)[n * 4 + lane] = make_float4(vx, vy, vz, vw);
    }
}

// ---------------------------------------------------------------------------
// k_out v4: wave = 64 nodes (thread = node); wave w owns classes c = w + 4i
// (wave-uniform -> W2/b2 scalar loads). Pass A: logits -> fp16 LDS + fmax only.
// Pass B: exp-sum with final max (one exp/class, no rescale chain).
#define SLP 174   // fp16 pad stride
__global__ __launch_bounds__(256) void k_out(const float* __restrict__ agg2,
                                             const float* __restrict__ W2,
                                             const float* __restrict__ b2,
                                             float* __restrict__ out) {
    __shared__ __half sl[64 * SLP];  // 22.3 KB logits [node][class] fp16
    __shared__ float pm[4][64];      // per-wave partial max
    __shared__ float ps[4][64];      // per-wave partial sumexp
    __shared__ float sls[64];        // per-node logsumexp
    int t   = threadIdx.x;
    int wid = __builtin_amdgcn_readfirstlane(t >> 6);  // wave id 0..3 (SGPR)
    int nl  = t & 63;
    int n   = blockIdx.x * 64 + nl;                    // grid exact: 3125*64

    const float4* ar = (const float4*)(agg2 + (size_t)n * 16);
    float4 a0 = ar[0], a1 = ar[1], a2 = ar[2], a3 = ar[3];
    float a[16] = {a0.x, a0.y, a0.z, a0.w, a1.x, a1.y, a1.z, a1.w,
                   a2.x, a2.y, a2.z, a2.w, a3.x, a3.y, a3.z, a3.w};

    float m = -INFINITY;
    __half* srow = sl + nl * SLP;
    for (int i = 0; i < 43; ++i) {             // c = wid + 4i <= 171 always
        int c = wid + 4 * i;                   // wave-uniform -> s_load W2
        float l = b2[c];
#pragma unroll
        for (int k = 0; k < 16; ++k) l += a[k] * W2[k * D_OUT + c];
        srow[c] = __float2half(l);
        m = fmaxf(m, l);
    }
    pm[wid][nl] = m;
    __syncthreads();
    float M = fmaxf(fmaxf(pm[0][nl], pm[1][nl]), fmaxf(pm[2][nl], pm[3][nl]));
    float s = 0.f;
    for (int i = 0; i < 43; ++i)
        s += __expf(__half2float(srow[wid + 4 * i]) - M);
    ps[wid][nl] = s;
    __syncthreads();
    if (wid == 0)
        sls[nl] = M + __logf(ps[0][nl] + ps[1][nl] + ps[2][nl] + ps[3][nl]);
    __syncthreads();
    // coalesced copy-out (log_softmax of the fp16-rounded logits: consistent)
    float* ob = out + (size_t)blockIdx.x * 64 * D_OUT;
    for (int idx = t; idx < 64 * D_OUT; idx += 256) {
        int node = idx / D_OUT, c = idx - node * D_OUT;
        ob[idx] = __half2float(sl[node * SLP + c]) - sls[node];
    }
}

// ---------------------------------------------------------------------------
extern "C" void kernel_launch(void* const* d_in, const int* in_sizes, int n_in,
                              void* d_out, int out_size, void* d_ws, size_t ws_size,
                              hipStream_t stream) {
    const float* x     = (const float*)d_in[0];
    const int*   edges = (const int*)d_in[1];
    const float* W1    = (const float*)d_in[2];
    const float* b1    = (const float*)d_in[3];
    const float* W2    = (const float*)d_in[4];
    const float* b2    = (const float*)d_in[5];
    float*       out   = (float*)d_out;

    const int* src = edges;
    const int* dst = edges + N_EDGES;

    unsigned* ws     = (unsigned*)d_ws;
    unsigned* btot   = ws + O_BTOT;
    unsigned* base   = ws + O_BASE;
    unsigned* counts = ws + O_CNT1;
    unsigned* scn    = ws + O_SCN;
    int*      col    = (int*)(ws + O_COL);      // aliases counts+scn (dead)
    int*      rowptr = (int*)(ws + O_ROW);
    float*    dinv   = (float*)(ws + O_DINV);
    unsigned* packed = ws + O_PACK;             // dead after k_csr
    __half*   f16a   = (__half*)(ws + O_F16A);  // aliases packed
    __half*   f16b   = (__half*)(ws + O_F16B);
    float*    agg2   = (float*)(ws + O_AGG2);

    // --- CSR build: zero global atomics ---
    k_hist1    <<<NS1, 256, 0, stream>>>(dst, counts);
    k_scan_col <<<SBN, 256, 0, stream>>>(counts, scn, btot);
    k_scan_base<<<1,    64, 0, stream>>>(btot, base);
    k_scatter1 <<<NS1, 256, 0, stream>>>(src, dst, counts, scn, base, packed);
    k_csr      <<<SBN, 256, 0, stream>>>(packed, base, rowptr, dinv, col);

    // --- layer 1: project 128->16 (pre-scaled, fp16), gather (relu fused) ---
    k_lin1     <<<N_NODES / 64, 256, 0, stream>>>(x, W1, dinv, f16a);
    k_gather<1><<<N_NODES / 64, 256, 0, stream>>>(rowptr, col, dinv,
                                                  (const uint2*)f16a, b1, f16b);

    // --- layer 2 (reassociated): gather h', then 16->172 + log_softmax ---
    k_gather<0><<<N_NODES / 64, 256, 0, stream>>>(rowptr, col, dinv,
                                                  (const uint2*)f16b, b1, agg2);
    k_out      <<<N_NODES / 64, 256, 0, stream>>>(agg2, W2, b2, out);
}